// Round 4
// baseline (440.424 us; speedup 1.0000x reference)
//
#include <hip/hip_runtime.h>

#define L  768
#define SD 384
#define PD 128
#define ROWS 4   // rows per phase1 block
#define TI 8     // i-rows per phase2 block
#define JPT 2    // j-rows per thread in phase2
#define TJ 16    // j-rows per phase2 block = 8 * JPT

typedef float vf4 __attribute__((ext_vector_type(4)));

// ws layout (floats): si[L*PD] | sj[L*PD] | u[L*PD] | v[L*PD]   (1.57 MB total)

__global__ __launch_bounds__(256) void phase1_kernel(
    const float* __restrict__ s,
    const float* __restrict__ wi, const float* __restrict__ bi,
    const float* __restrict__ wj, const float* __restrict__ bj,
    const float* __restrict__ wm, const float* __restrict__ bm,
    float* __restrict__ ws)
{
    __shared__ float s_t[ROWS][SD];          // 6 KB
    __shared__ float sij_t[2][ROWS][PD];     // 4 KB
    const int tid = threadIdx.x;
    const int r0  = blockIdx.x * ROWS;

    // stage 4 rows of s into LDS, coalesced
    for (int idx = tid; idx < ROWS * SD; idx += 256) {
        s_t[idx / SD][idx % SD] = s[(size_t)r0 * SD + idx];
    }
    __syncthreads();

    const int half = tid >> 7;        // wave-uniform: waves 0-1 -> si, waves 2-3 -> sj
    const int e    = tid & 127;       // output channel
    const float* wrow = (half ? wj : wi) + (size_t)e * SD;
    const float  bb   = (half ? bj : bi)[e];

    // si[r][e] / sj[r][e] = dot(s[r], w[e]) + b[e]
    float acc[ROWS] = {0.f, 0.f, 0.f, 0.f};
    const vf4* w4 = (const vf4*)wrow;
    for (int d4 = 0; d4 < SD / 4; ++d4) {
        const vf4 wv = w4[d4];
        #pragma unroll
        for (int r = 0; r < ROWS; ++r) {
            const vf4 sv = ((const vf4*)s_t[r])[d4];   // LDS broadcast, b128
            acc[r] += sv.x * wv.x + sv.y * wv.y + sv.z * wv.z + sv.w * wv.w;
        }
    }

    float* si_ws = ws;
    float* sj_ws = ws + (size_t)L * PD;
    float* u_ws  = ws + 2 * (size_t)L * PD;
    float* v_ws  = ws + 3 * (size_t)L * PD;

    float* sij_ws = half ? sj_ws : si_ws;
    #pragma unroll
    for (int r = 0; r < ROWS; ++r) {
        const float val = acc[r] + bb;
        sij_t[half][r][e] = val;
        sij_ws[(size_t)(r0 + r) * PD + e] = val;
    }
    __syncthreads();

    // u[r][e] = dot(si[r], wm[e, 0:128]) ; v[r][e] = dot(sj[r], wm[e, 128:256]) + bm[e]
    const vf4* wm4 = (const vf4*)(wm + (size_t)e * (2 * PD) + half * PD);
    float acc2[ROWS] = {0.f, 0.f, 0.f, 0.f};
    for (int d4 = 0; d4 < PD / 4; ++d4) {
        const vf4 wv = wm4[d4];
        #pragma unroll
        for (int r = 0; r < ROWS; ++r) {
            const vf4 sv = ((const vf4*)sij_t[half][r])[d4];
            acc2[r] += sv.x * wv.x + sv.y * wv.y + sv.z * wv.z + sv.w * wv.w;
        }
    }
    const float bm_e = bm[e];
    float* z_ws = half ? v_ws : u_ws;
    #pragma unroll
    for (int r = 0; r < ROWS; ++r) {
        z_ws[(size_t)(r0 + r) * PD + e] = acc2[r] + (half ? bm_e : 0.f);
    }
}

// out[i,j,e] = u[i,e] + v[j,e] + si[i,e]*sj[j,e]
//
// v4 = DIAGNOSTIC round. Kernel bodies byte-identical to the passing v3.
// Three phase2 variants (nt-store, 3.2x load reduction, occupancy 4.5->8
// waves/SIMD, tile reshape) were ALL neutral within 0.3% -> the time
// attribution model is broken. Launching phase2 three times (idempotent:
// identical values overwritten) makes dur_us = base + 2*p2, measuring
// phase2's true duration regardless of what else is in the timed window:
//   dur ~609 us -> p2~135 (phase2 stuck at 2.2 TB/s, mechanism unknown)
//   dur ~439 us -> p2~50  (phase2 AT write roofline; phase1 is the pig)
__global__ __launch_bounds__(256) void phase2_kernel(
    const float* __restrict__ ws, float* __restrict__ out)
{
    const int i0 = blockIdx.y * TI;
    const int j0 = blockIdx.x * TJ;
    const int q  = threadIdx.x & 31;   // float4 index within 128 channels
    const int jj = threadIdx.x >> 5;   // 0..7

    const vf4* si = (const vf4*)(ws);
    const vf4* sj = (const vf4*)(ws + (size_t)L * PD);
    const vf4* u  = (const vf4*)(ws + 2 * (size_t)L * PD);
    const vf4* v  = (const vf4*)(ws + 3 * (size_t)L * PD);

    vf4 vj[JPT], sjj[JPT];
    #pragma unroll
    for (int k = 0; k < JPT; ++k) {
        const int j = j0 + jj + 8 * k;
        vj[k]  = v [(size_t)j * 32 + q];
        sjj[k] = sj[(size_t)j * 32 + q];
    }

    vf4* o = (vf4*)out;
    #pragma unroll
    for (int il = 0; il < TI; ++il) {
        const int i = i0 + il;
        const vf4 s4 = si[(size_t)i * 32 + q];
        const vf4 u4 = u [(size_t)i * 32 + q];
        #pragma unroll
        for (int k = 0; k < JPT; ++k) {
            const int j = j0 + jj + 8 * k;
            o[((size_t)i * L + j) * 32 + q] = u4 + vj[k] + s4 * sjj[k];
        }
    }
}

extern "C" void kernel_launch(void* const* d_in, const int* in_sizes, int n_in,
                              void* d_out, int out_size, void* d_ws, size_t ws_size,
                              hipStream_t stream) {
    const float* s  = (const float*)d_in[0];
    const float* wi = (const float*)d_in[1];
    const float* bi = (const float*)d_in[2];
    const float* wj = (const float*)d_in[3];
    const float* bj = (const float*)d_in[4];
    const float* wm = (const float*)d_in[5];
    const float* bm = (const float*)d_in[6];
    float* out = (float*)d_out;
    float* ws  = (float*)d_ws;   // needs 4*L*PD*4 = 1.57 MB

    phase1_kernel<<<dim3(L / ROWS), 256, 0, stream>>>(s, wi, bi, wj, bj, wm, bm, ws);
    // DIAGNOSTIC: 3x idempotent phase2 -> dur_us = base + 2*p2.
    for (int rep = 0; rep < 3; ++rep) {
        phase2_kernel<<<dim3(L / TJ, L / TI), 256, 0, stream>>>(ws, out);
    }
}

// Round 5
// 351.606 us; speedup vs baseline: 1.2526x; 1.2526x over previous
//
#include <hip/hip_runtime.h>

#define L  768
#define SD 384
#define PD 128
#define TI 8     // i-rows per phase2 block
#define JPT 2    // j-rows per thread in phase2
#define TJ 16    // j-rows per phase2 block = 8 * JPT

typedef float vf4 __attribute__((ext_vector_type(4)));

// ws layout (floats): si[L*PD] | sj[L*PD] | u[L*PD] | v[L*PD]   (1.57 MB total)

// ---------------------------------------------------------------------------
// Phase A: si/sj = s @ {wi,wj}^T + {bi,bj}
// GEMM M=L=768, N=2*PD=256, K=SD=384. Tile 32x32, K in 2 chunks of 192.
// v5: replaces the old phase1's uncoalesced per-thread weight-row reads
// (64 cache lines per wave-load, 0.75 blocks/CU) with LDS-staged operands:
// all global loads coalesced vf4, grid (24,8)=192 blocks.
// ---------------------------------------------------------------------------
#define A_BM 32
#define A_BN 32
#define A_BK 192
#define A_LDK (A_BK + 4)   // 196: keeps 16B alignment, shifts banks by 4/row

__global__ __launch_bounds__(256) void phaseA_kernel(
    const float* __restrict__ s,
    const float* __restrict__ wi, const float* __restrict__ bi,
    const float* __restrict__ wj, const float* __restrict__ bj,
    float* __restrict__ ws)
{
    __shared__ float sT[A_BM][A_LDK];   // 24.5 KB
    __shared__ float wT[A_BN][A_LDK];   // 24.5 KB
    const int tid  = threadIdx.x;
    const int r0   = blockIdx.x * A_BM;
    const int cb   = blockIdx.y;            // 0..7
    const int half = cb >> 2;               // 0: si (wi,bi), 1: sj (wj,bj)
    const int c0   = (cb & 3) * A_BN;       // channel base within PD
    const float* w = (half ? wj : wi) + (size_t)c0 * SD;
    const float* b = (half ? bj : bi) + c0;
    float* out = ws + (size_t)half * L * PD;

    const int tx = tid & 31;    // row within tile
    const int ty = tid >> 5;    // 0..7 -> channels ty*4 .. ty*4+3

    vf4 acc[4] = {vf4{0,0,0,0}, vf4{0,0,0,0}, vf4{0,0,0,0}, vf4{0,0,0,0}};

    for (int k0 = 0; k0 < SD; k0 += A_BK) {
        // stage sT: 32 rows x 192 floats (coalesced vf4)
        for (int idx = tid; idx < A_BM * (A_BK / 4); idx += 256) {
            const int rr = idx / (A_BK / 4), kk = idx % (A_BK / 4);
            *(vf4*)&sT[rr][kk * 4] =
                *(const vf4*)&s[(size_t)(r0 + rr) * SD + k0 + kk * 4];
        }
        // stage wT: 32 channel-rows x 192 floats (coalesced vf4)
        for (int idx = tid; idx < A_BN * (A_BK / 4); idx += 256) {
            const int cc = idx / (A_BK / 4), kk = idx % (A_BK / 4);
            *(vf4*)&wT[cc][kk * 4] =
                *(const vf4*)&w[(size_t)cc * SD + k0 + kk * 4];
        }
        __syncthreads();
        for (int k4 = 0; k4 < A_BK / 4; ++k4) {
            const vf4 s4 = *(const vf4*)&sT[tx][k4 * 4];   // 4-way bank, ok
            #pragma unroll
            for (int cc = 0; cc < 4; ++cc) {
                const vf4 w4 = *(const vf4*)&wT[ty * 4 + cc][k4 * 4]; // 2-way
                acc[cc] += s4 * w4;
            }
        }
        __syncthreads();
    }

    vf4 o;
    #pragma unroll
    for (int cc = 0; cc < 4; ++cc) {
        o[cc] = acc[cc].x + acc[cc].y + acc[cc].z + acc[cc].w + b[ty * 4 + cc];
    }
    *(vf4*)&out[(size_t)(r0 + tx) * PD + c0 + ty * 4] = o;
}

// ---------------------------------------------------------------------------
// Phase B: u = si @ wm[:, :PD]^T ; v = sj @ wm[:, PD:]^T + bm
// GEMM M=768, N=256 (u:128|v:128), K=128. Tile 32x32, grid (24,8).
// Reads si/sj from ws (L2-hot), writes u/v to ws.
// ---------------------------------------------------------------------------
#define B_LDK (PD + 4)   // 132

__global__ __launch_bounds__(256) void phaseB_kernel(
    const float* __restrict__ wm, const float* __restrict__ bm,
    float* __restrict__ ws)
{
    __shared__ float xT[32][B_LDK];   // 16.9 KB
    __shared__ float wT[32][B_LDK];   // 16.9 KB
    const int tid  = threadIdx.x;
    const int r0   = blockIdx.x * 32;
    const int cb   = blockIdx.y;            // 0..7
    const int half = cb >> 2;               // 0: u (from si), 1: v (from sj, +bm)
    const int e0   = (cb & 3) * 32;
    const float* x = ws + (size_t)half * L * PD;        // si or sj
    float* out     = ws + (size_t)(2 + half) * L * PD;  // u or v

    // stage xT: 32 rows x 128 floats
    for (int idx = tid; idx < 32 * (PD / 4); idx += 256) {
        const int rr = idx / (PD / 4), kk = idx % (PD / 4);
        *(vf4*)&xT[rr][kk * 4] = *(const vf4*)&x[(size_t)(r0 + rr) * PD + kk * 4];
    }
    // stage wT: 32 wm-rows x 128 floats (column half selects wm[:, :PD] / wm[:, PD:])
    for (int idx = tid; idx < 32 * (PD / 4); idx += 256) {
        const int cc = idx / (PD / 4), kk = idx % (PD / 4);
        *(vf4*)&wT[cc][kk * 4] =
            *(const vf4*)&wm[(size_t)(e0 + cc) * (2 * PD) + half * PD + kk * 4];
    }
    __syncthreads();

    const int tx = tid & 31;
    const int ty = tid >> 5;

    vf4 acc[4] = {vf4{0,0,0,0}, vf4{0,0,0,0}, vf4{0,0,0,0}, vf4{0,0,0,0}};
    for (int k4 = 0; k4 < PD / 4; ++k4) {
        const vf4 x4 = *(const vf4*)&xT[tx][k4 * 4];
        #pragma unroll
        for (int cc = 0; cc < 4; ++cc) {
            const vf4 w4 = *(const vf4*)&wT[ty * 4 + cc][k4 * 4];
            acc[cc] += x4 * w4;
        }
    }

    vf4 o;
    #pragma unroll
    for (int cc = 0; cc < 4; ++cc) {
        const float bias = half ? bm[e0 + ty * 4 + cc] : 0.f;
        o[cc] = acc[cc].x + acc[cc].y + acc[cc].z + acc[cc].w + bias;
    }
    *(vf4*)&out[(size_t)(r0 + tx) * PD + e0 + ty * 4] = o;
}

// ---------------------------------------------------------------------------
// Phase 2: out[i,j,e] = u[i,e] + v[j,e] + si[i,e]*sj[j,e]
// Measured AT the write roofline (round-4 diagnostic: 50.7 us vs 48.7 ideal).
// Unchanged from the passing v3.
// ---------------------------------------------------------------------------
__global__ __launch_bounds__(256) void phase2_kernel(
    const float* __restrict__ ws, float* __restrict__ out)
{
    const int i0 = blockIdx.y * TI;
    const int j0 = blockIdx.x * TJ;
    const int q  = threadIdx.x & 31;   // float4 index within 128 channels
    const int jj = threadIdx.x >> 5;   // 0..7

    const vf4* si = (const vf4*)(ws);
    const vf4* sj = (const vf4*)(ws + (size_t)L * PD);
    const vf4* u  = (const vf4*)(ws + 2 * (size_t)L * PD);
    const vf4* v  = (const vf4*)(ws + 3 * (size_t)L * PD);

    vf4 vj[JPT], sjj[JPT];
    #pragma unroll
    for (int k = 0; k < JPT; ++k) {
        const int j = j0 + jj + 8 * k;
        vj[k]  = v [(size_t)j * 32 + q];
        sjj[k] = sj[(size_t)j * 32 + q];
    }

    vf4* o = (vf4*)out;
    #pragma unroll
    for (int il = 0; il < TI; ++il) {
        const int i = i0 + il;
        const vf4 s4 = si[(size_t)i * 32 + q];
        const vf4 u4 = u [(size_t)i * 32 + q];
        #pragma unroll
        for (int k = 0; k < JPT; ++k) {
            const int j = j0 + jj + 8 * k;
            o[((size_t)i * L + j) * 32 + q] = u4 + vj[k] + s4 * sjj[k];
        }
    }
}

extern "C" void kernel_launch(void* const* d_in, const int* in_sizes, int n_in,
                              void* d_out, int out_size, void* d_ws, size_t ws_size,
                              hipStream_t stream) {
    const float* s  = (const float*)d_in[0];
    const float* wi = (const float*)d_in[1];
    const float* bi = (const float*)d_in[2];
    const float* wj = (const float*)d_in[3];
    const float* bj = (const float*)d_in[4];
    const float* wm = (const float*)d_in[5];
    const float* bm = (const float*)d_in[6];
    float* out = (float*)d_out;
    float* ws  = (float*)d_ws;   // needs 4*L*PD*4 = 1.57 MB

    phaseA_kernel<<<dim3(L / A_BM, 8), 256, 0, stream>>>(s, wi, bi, wj, bj, ws);
    phaseB_kernel<<<dim3(L / 32, 8), 256, 0, stream>>>(wm, bm, ws);
    phase2_kernel<<<dim3(L / TJ, L / TI), 256, 0, stream>>>(ws, out);
}

// Round 6
// 328.111 us; speedup vs baseline: 1.3423x; 1.0716x over previous
//
#include <hip/hip_runtime.h>

#define L  768
#define SD 384
#define PD 128
#define ROWS 4   // rows per phase1 block
#define TI 8     // i-rows per phase2 block
#define JPT 2    // j-rows per thread in phase2
#define TJ 16    // j-rows per phase2 block = 8 * JPT

typedef float vf4 __attribute__((ext_vector_type(4)));

// ws layout (floats): si[L*PD] | sj[L*PD] | u[L*PD] | v[L*PD]   (1.57 MB total)

// v6 phase1: round-3 structure + split-K across a 512-thread block.
// Evidence trail: p2 is AT the write roofline (r4 diagnostic: 50.7 us vs
// 48.7 ideal); GEMM-restructured phase1 (r5) was 12.5 us SLOWER than this
// structure -> old p1 is small (~15-20 us) and latency-bound (192 blocks =
// 1 wave/SIMD, nothing hides the w-load latency; L1 absorbs the line
// overfetch since each thread reuses its 64B lines across 4 k4-iters).
// Fix: tid bit 8 selects a K-half; partials combine via a 4 KB LDS buffer.
// Same global traffic, 2x waves/SIMD for latency hiding.
__global__ __launch_bounds__(512) void phase1_kernel(
    const float* __restrict__ s,
    const float* __restrict__ wi, const float* __restrict__ bi,
    const float* __restrict__ wj, const float* __restrict__ bj,
    const float* __restrict__ wm, const float* __restrict__ bm,
    float* __restrict__ ws)
{
    __shared__ float s_t[ROWS][SD];          // 6 KB
    __shared__ float sij_t[2][ROWS][PD];     // 4 KB
    __shared__ float part[2][ROWS][PD];      // 4 KB: g=1 half's partials
    const int tid = threadIdx.x;
    const int r0  = blockIdx.x * ROWS;

    // stage 4 rows of s into LDS, coalesced (1536 = 3*512)
    for (int idx = tid; idx < ROWS * SD; idx += 512) {
        s_t[idx / SD][idx % SD] = s[(size_t)r0 * SD + idx];
    }
    __syncthreads();

    const int g    = tid >> 8;        // K-half (wave-uniform)
    const int half = (tid >> 7) & 1;  // 0: si/u, 1: sj/v (wave-uniform)
    const int e    = tid & 127;       // output channel
    const float* wrow = (half ? wj : wi) + (size_t)e * SD;
    const float  bb   = (half ? bj : bi)[e];

    // mm1 partial: dot(s[r][gK:gK+192], w[e][gK:gK+192])
    float acc[ROWS] = {0.f, 0.f, 0.f, 0.f};
    const vf4* w4 = (const vf4*)wrow + g * (SD / 8);
    for (int d4 = 0; d4 < SD / 8; ++d4) {
        const vf4 wv = w4[d4];
        #pragma unroll
        for (int r = 0; r < ROWS; ++r) {
            const vf4 sv = ((const vf4*)s_t[r])[g * (SD / 8) + d4];  // broadcast
            acc[r] += sv.x * wv.x + sv.y * wv.y + sv.z * wv.z + sv.w * wv.w;
        }
    }

    float* si_ws = ws;
    float* sj_ws = ws + (size_t)L * PD;
    float* u_ws  = ws + 2 * (size_t)L * PD;
    float* v_ws  = ws + 3 * (size_t)L * PD;

    if (g) {
        #pragma unroll
        for (int r = 0; r < ROWS; ++r) part[half][r][e] = acc[r];   // 2 lanes/bank: free
    }
    __syncthreads();
    if (!g) {
        float* sij_ws = half ? sj_ws : si_ws;
        #pragma unroll
        for (int r = 0; r < ROWS; ++r) {
            const float val = acc[r] + part[half][r][e] + bb;
            sij_t[half][r][e] = val;
            sij_ws[(size_t)(r0 + r) * PD + e] = val;   // coalesced 256B/row
        }
    }
    __syncthreads();   // sij_t ready; part free for reuse

    // mm2 partial: u[r][e] = dot(si[r], wm[e,0:128]); v[r][e] = dot(sj[r], wm[e,128:256]) + bm
    const vf4* wm4 = (const vf4*)(wm + (size_t)e * (2 * PD) + half * PD) + g * (PD / 8);
    float acc2[ROWS] = {0.f, 0.f, 0.f, 0.f};
    for (int d4 = 0; d4 < PD / 8; ++d4) {
        const vf4 wv = wm4[d4];
        #pragma unroll
        for (int r = 0; r < ROWS; ++r) {
            const vf4 sv = ((const vf4*)sij_t[half][r])[g * (PD / 8) + d4];  // broadcast
            acc2[r] += sv.x * wv.x + sv.y * wv.y + sv.z * wv.z + sv.w * wv.w;
        }
    }
    if (g) {
        #pragma unroll
        for (int r = 0; r < ROWS; ++r) part[half][r][e] = acc2[r];
    }
    __syncthreads();
    if (!g) {
        const float bm_e = bm[e];
        float* z_ws = half ? v_ws : u_ws;
        #pragma unroll
        for (int r = 0; r < ROWS; ++r) {
            z_ws[(size_t)(r0 + r) * PD + e] =
                acc2[r] + part[half][r][e] + (half ? bm_e : 0.f);
        }
    }
}

// out[i,j,e] = u[i,e] + v[j,e] + si[i,e]*sj[j,e]
// Measured AT the write roofline (r4 diagnostic: 50.7 us vs 48.7 ideal;
// nt-store / load-volume / occupancy all proven neutral). Byte-identical
// to the round-3 passing version. DO NOT TOUCH.
__global__ __launch_bounds__(256) void phase2_kernel(
    const float* __restrict__ ws, float* __restrict__ out)
{
    const int i0 = blockIdx.y * TI;
    const int j0 = blockIdx.x * TJ;
    const int q  = threadIdx.x & 31;   // float4 index within 128 channels
    const int jj = threadIdx.x >> 5;   // 0..7

    const vf4* si = (const vf4*)(ws);
    const vf4* sj = (const vf4*)(ws + (size_t)L * PD);
    const vf4* u  = (const vf4*)(ws + 2 * (size_t)L * PD);
    const vf4* v  = (const vf4*)(ws + 3 * (size_t)L * PD);

    vf4 vj[JPT], sjj[JPT];
    #pragma unroll
    for (int k = 0; k < JPT; ++k) {
        const int j = j0 + jj + 8 * k;
        vj[k]  = v [(size_t)j * 32 + q];
        sjj[k] = sj[(size_t)j * 32 + q];
    }

    vf4* o = (vf4*)out;
    #pragma unroll
    for (int il = 0; il < TI; ++il) {
        const int i = i0 + il;
        const vf4 s4 = si[(size_t)i * 32 + q];
        const vf4 u4 = u [(size_t)i * 32 + q];
        #pragma unroll
        for (int k = 0; k < JPT; ++k) {
            const int j = j0 + jj + 8 * k;
            o[((size_t)i * L + j) * 32 + q] = u4 + vj[k] + s4 * sjj[k];
        }
    }
}

extern "C" void kernel_launch(void* const* d_in, const int* in_sizes, int n_in,
                              void* d_out, int out_size, void* d_ws, size_t ws_size,
                              hipStream_t stream) {
    const float* s  = (const float*)d_in[0];
    const float* wi = (const float*)d_in[1];
    const float* bi = (const float*)d_in[2];
    const float* wj = (const float*)d_in[3];
    const float* bj = (const float*)d_in[4];
    const float* wm = (const float*)d_in[5];
    const float* bm = (const float*)d_in[6];
    float* out = (float*)d_out;
    float* ws  = (float*)d_ws;   // needs 4*L*PD*4 = 1.57 MB

    phase1_kernel<<<dim3(L / ROWS), 512, 0, stream>>>(s, wi, bi, wj, bj, wm, bm, ws);
    phase2_kernel<<<dim3(L / TJ, L / TI), 256, 0, stream>>>(ws, out);
}